// Round 1
// baseline (230.473 us; speedup 1.0000x reference)
//
#include <hip/hip_runtime.h>
#include <hip/hip_bf16.h>

// EfficientSelfAttn (PVT spatial-reduction attention), fp32.
// B=8, N=16384, C=64, NH=1, SR=8, H=W=128 -> Nk=256.
//
// k0: weight reorder into ws (transposed layouts for coalesced loads)
// k1: conv(8x8 s8) + LayerNorm + KV-proj -> kT[b][ic][m], v[b][m][c]
// k2: per 64-row tile: q-proj -> S=q.kT -> softmax -> P.v -> out-proj

namespace {

constexpr int kN = 16384;

// ws layout in floats
constexpr size_t WS_WSRT   = 0;        // [r=kh*8+kw][ic][oc] : 64*64*64
constexpr size_t WS_WQT    = 262144;   // [ic][c] : 64*64
constexpr size_t WS_WKVT   = 266240;   // [c][j] : 64*128
constexpr size_t WS_WPROJT = 274432;   // [d][c] : 64*64
constexpr size_t WS_KT     = 278528;   // [b][ic][m] : 8*64*256
constexpr size_t WS_V      = 409600;   // [b][m][c]  : 8*256*64

__global__ __launch_bounds__(256) void k0_reorder(
    const float* __restrict__ wq, const float* __restrict__ wkv,
    const float* __restrict__ wproj, const float* __restrict__ wsr,
    float* __restrict__ ws) {
  int e = blockIdx.x * 256 + threadIdx.x;
  if (e < 262144) {
    int oc = e & 63, ic = (e >> 6) & 63, r = e >> 12;
    ws[WS_WSRT + e] = wsr[oc * 4096 + ic * 64 + r];
  } else if (e < 266240) {
    int i = e - 262144;
    int c = i & 63, ic = i >> 6;
    ws[WS_WQT + i] = wq[c * 64 + ic];
  } else if (e < 274432) {
    int i = e - 266240;
    int j = i & 127, c = i >> 7;
    ws[WS_WKVT + i] = wkv[j * 64 + c];
  } else if (e < 278528) {
    int i = e - 274432;
    int c = i & 63, d = i >> 6;
    ws[WS_WPROJT + i] = wproj[c * 64 + d];
  }
}

// ---- k1: conv + LN + KV ----------------------------------------------------
// grid: 256 = 8 batches * 32 patch-groups (8 patches each). 256 threads.
// thread: ocp = t&31 handles oc in {ocp, ocp+32}; icg = t>>5 handles ic icg*8..+7
__global__ __launch_bounds__(256) void k1_conv_ln_kv(
    const float* __restrict__ x, const float* __restrict__ bkv,
    const float* __restrict__ gamma, const float* __restrict__ beta,
    float* __restrict__ ws) {
  const float* __restrict__ wsrT = ws + WS_WSRT;
  const float* __restrict__ wkvT = ws + WS_WKVT;
  float* __restrict__ kT = ws + WS_KT;
  float* __restrict__ vv = ws + WS_V;

  const int b  = blockIdx.x >> 5;
  const int pg = blockIdx.x & 31;
  const int t  = threadIdx.x;
  const int ocp = t & 31;
  const int icg = t >> 5;

  __shared__ float chunk[4096];  // [p][kw][ic] for one kh slab
  __shared__ float red[4096];    // [icg][oc*8+p]
  __shared__ float cvout[512];   // [p][oc]
  __shared__ float xnl[512];     // [p][oc]

  const float* __restrict__ xb = x + (size_t)b * (kN * 64);

  float acc0[8], acc1[8];
#pragma unroll
  for (int p = 0; p < 8; ++p) { acc0[p] = 0.f; acc1[p] = 0.f; }

  for (int kh = 0; kh < 8; ++kh) {
    __syncthreads();
    // stage: 8 patches x 8 rows(kw) x 64 ch; each patch slab is 512 contiguous floats
#pragma unroll
    for (int it = 0; it < 4; ++it) {
      int f = it * 1024 + t * 4;
      int p = f >> 9;
      int w512 = f & 511;
      int pid = pg * 8 + p;
      int oh = pid >> 4, ow = pid & 15;
      const float* src = xb + oh * 65536 + ow * 512 + kh * 8192 + w512;
      *(float4*)&chunk[f] = *(const float4*)src;
    }
    __syncthreads();
    for (int kw = 0; kw < 8; ++kw) {
      const int rbase = ((kh * 8 + kw) * 64 + icg * 8) * 64;
      float w0[8], w1[8];
#pragma unroll
      for (int ii = 0; ii < 8; ++ii) {
        w0[ii] = wsrT[rbase + ii * 64 + ocp];
        w1[ii] = wsrT[rbase + ii * 64 + ocp + 32];
      }
#pragma unroll
      for (int p = 0; p < 8; ++p) {
        const float* cp = &chunk[p * 512 + kw * 64 + icg * 8];
        float4 a = *(const float4*)cp;
        float4 bb = *(const float4*)(cp + 4);
        float xs[8] = {a.x, a.y, a.z, a.w, bb.x, bb.y, bb.z, bb.w};
#pragma unroll
        for (int ii = 0; ii < 8; ++ii) {
          acc0[p] = fmaf(w0[ii], xs[ii], acc0[p]);
          acc1[p] = fmaf(w1[ii], xs[ii], acc1[p]);
        }
      }
    }
  }

  // reduce partial ic groups
#pragma unroll
  for (int p = 0; p < 8; ++p) {
    red[icg * 512 + ocp * 8 + p] = acc0[p];
    red[icg * 512 + (ocp + 32) * 8 + p] = acc1[p];
  }
  __syncthreads();
#pragma unroll
  for (int u = 0; u < 2; ++u) {
    int e = t * 2 + u;  // e = oc*8 + p
    float s = 0.f;
#pragma unroll
    for (int g = 0; g < 8; ++g) s += red[g * 512 + e];
    cvout[(e & 7) * 64 + (e >> 3)] = s;
  }
  __syncthreads();

  // LayerNorm over channels: wave w handles patches 2w, 2w+1; lane = channel
  const int lane = t & 63;
  const int wid = t >> 6;
#pragma unroll
  for (int pp = 0; pp < 2; ++pp) {
    int p = wid * 2 + pp;
    float val = cvout[p * 64 + lane];
    float ssum = val;
#pragma unroll
    for (int off = 1; off < 64; off <<= 1) ssum += __shfl_xor(ssum, off);
    float mean = ssum * (1.f / 64.f);
    float dv = val - mean;
    float sq = dv * dv;
#pragma unroll
    for (int off = 1; off < 64; off <<= 1) sq += __shfl_xor(sq, off);
    float rs = 1.0f / sqrtf(sq * (1.f / 64.f) + 1e-5f);
    xnl[p * 64 + lane] = dv * rs * gamma[lane] + beta[lane];
  }
  __syncthreads();

  // KV projection: thread: pgk = t>>7 (4 patches), j = t&127
  const int pgk = t >> 7;
  const int j = t & 127;
  float a4[4] = {0.f, 0.f, 0.f, 0.f};
  for (int c = 0; c < 64; ++c) {
    float w = wkvT[c * 128 + j];
#pragma unroll
    for (int q = 0; q < 4; ++q)
      a4[q] = fmaf(xnl[(pgk * 4 + q) * 64 + c], w, a4[q]);
  }
  float bj = bkv[j];
#pragma unroll
  for (int q = 0; q < 4; ++q) {
    int p = pgk * 4 + q;
    int pid = pg * 8 + p;
    float val = a4[q] + bj;
    if (j < 64) kT[(size_t)b * 16384 + j * 256 + pid] = val;
    else        vv[(size_t)b * 16384 + pid * 64 + (j - 64)] = val;
  }
}

// ---- k2: q-proj + attention + out-proj -------------------------------------
// grid: 2048 = 8 batches * 256 row-blocks (64 rows). 256 threads, 48KB LDS.
__global__ __launch_bounds__(256) void k2_attn(
    const float* __restrict__ x, const float* __restrict__ bq,
    const float* __restrict__ bproj, const float* __restrict__ ws,
    float* __restrict__ out) {
  const float* __restrict__ wqT = ws + WS_WQT;
  const float* __restrict__ wpT = ws + WS_WPROJT;

  const int b  = blockIdx.x >> 8;
  const int rb = blockIdx.x & 255;
  const int n0 = rb * 64;
  const int t = threadIdx.x;
  const int lane = t & 63, wid = t >> 6;
  const int rg2 = t >> 4, cg2 = t & 15;

  const float* __restrict__ kTb = ws + WS_KT + (size_t)b * 16384;
  const float* __restrict__ vb  = ws + WS_V  + (size_t)b * 16384;

  __shared__ float R1[8192];  // x-tile(64x68) -> kT half(32x256) -> P half(64x128) -> O(64x64)
  __shared__ float R2[4096];  // qT swizzled [c][r-quads]

  const float* __restrict__ xb = x + ((size_t)b * kN + n0) * 64;

  // stage x tile padded [64][68]
#pragma unroll
  for (int it = 0; it < 4; ++it) {
    int f = it * 1024 + t * 4;
    int r = f >> 6, c = f & 63;
    *(float4*)&R1[r * 68 + c] = *(const float4*)(xb + f);
  }
  __syncthreads();

  // A: q = x @ wq^T (+bq), scale by 1/8, write swizzled qT -> R2
  {
    float qa[4][4];
#pragma unroll
    for (int i = 0; i < 4; ++i)
#pragma unroll
      for (int jj = 0; jj < 4; ++jj) qa[i][jj] = 0.f;

    for (int ic4 = 0; ic4 < 16; ++ic4) {
      float xs[4][4];
#pragma unroll
      for (int i = 0; i < 4; ++i) {
        float4 xr = *(const float4*)&R1[(rg2 * 4 + i) * 68 + ic4 * 4];
        xs[i][0] = xr.x; xs[i][1] = xr.y; xs[i][2] = xr.z; xs[i][3] = xr.w;
      }
#pragma unroll
      for (int u = 0; u < 4; ++u) {
        const float4 w4 = *(const float4*)(wqT + (ic4 * 4 + u) * 64 + cg2 * 4);
        const float wj[4] = {w4.x, w4.y, w4.z, w4.w};
#pragma unroll
        for (int i = 0; i < 4; ++i)
#pragma unroll
          for (int jj = 0; jj < 4; ++jj)
            qa[i][jj] = fmaf(xs[i][u], wj[jj], qa[i][jj]);
      }
    }
#pragma unroll
    for (int jj = 0; jj < 4; ++jj) {
      int c = cg2 * 4 + jj;
      float bias = bq[c];
      float4 o4;
      o4.x = (qa[0][jj] + bias) * 0.125f;
      o4.y = (qa[1][jj] + bias) * 0.125f;
      o4.z = (qa[2][jj] + bias) * 0.125f;
      o4.w = (qa[3][jj] + bias) * 0.125f;
      *(float4*)&R2[c * 64 + ((rg2 ^ (c & 15)) << 2)] = o4;
    }
  }
  __syncthreads();  // qT visible; x-tile reads complete

  // B: S[16 rows][4 m] per lane; wave wid owns rows wid*16..+15, lane owns m=lane*4..+3
  float S[16][4];
#pragma unroll
  for (int i = 0; i < 16; ++i)
#pragma unroll
    for (int jj = 0; jj < 4; ++jj) S[i][jj] = 0.f;

  for (int half = 0; half < 2; ++half) {
    // stage kT half: [32 ic][256 m] linear
#pragma unroll
    for (int it = 0; it < 8; ++it) {
      int f = it * 1024 + t * 4;
      *(float4*)&R1[f] = *(const float4*)(kTb + half * 8192 + f);
    }
    __syncthreads();
#pragma unroll 2
    for (int icl = 0; icl < 32; ++icl) {
      const int ic = half * 32 + icl;
      float qs[16];
#pragma unroll
      for (int cc = 0; cc < 4; ++cc) {
        const int qq = wid * 4 + cc;
        const float4 q4 = *(const float4*)&R2[ic * 64 + ((qq ^ (ic & 15)) << 2)];
        qs[cc * 4 + 0] = q4.x; qs[cc * 4 + 1] = q4.y;
        qs[cc * 4 + 2] = q4.z; qs[cc * 4 + 3] = q4.w;
      }
      const float4 k4 = *(const float4*)&R1[icl * 256 + lane * 4];
      const float kk[4] = {k4.x, k4.y, k4.z, k4.w};
#pragma unroll
      for (int i = 0; i < 16; ++i)
#pragma unroll
        for (int jj = 0; jj < 4; ++jj)
          S[i][jj] = fmaf(qs[i], kk[jj], S[i][jj]);
    }
    __syncthreads();
  }

  // softmax over 256 keys per row (full-wave reductions)
#pragma unroll
  for (int i = 0; i < 16; ++i) {
    float m = fmaxf(fmaxf(S[i][0], S[i][1]), fmaxf(S[i][2], S[i][3]));
#pragma unroll
    for (int off = 1; off < 64; off <<= 1) m = fmaxf(m, __shfl_xor(m, off));
    float s = 0.f;
#pragma unroll
    for (int jj = 0; jj < 4; ++jj) { S[i][jj] = __expf(S[i][jj] - m); s += S[i][jj]; }
#pragma unroll
    for (int off = 1; off < 64; off <<= 1) s += __shfl_xor(s, off);
    float inv = 1.0f / s;
#pragma unroll
    for (int jj = 0; jj < 4; ++jj) S[i][jj] *= inv;
  }

  // D: O = P @ v, P halves through R1 (XOR-quad swizzled), v from global (L2-hot)
  float oa[4][4];
#pragma unroll
  for (int i = 0; i < 4; ++i)
#pragma unroll
    for (int jj = 0; jj < 4; ++jj) oa[i][jj] = 0.f;

  for (int half = 0; half < 2; ++half) {
    if ((lane >> 5) == half) {
      const int mq = lane & 31;  // local m-quad in this half
#pragma unroll
      for (int i = 0; i < 16; ++i) {
        const int r = wid * 16 + i;
        *(float4*)&R1[r * 128 + ((mq ^ (r & 15)) << 2)] =
            make_float4(S[i][0], S[i][1], S[i][2], S[i][3]);
      }
    }
    __syncthreads();
#pragma unroll 2
    for (int mq = 0; mq < 32; ++mq) {
      float pq[4][4];
#pragma unroll
      for (int i2 = 0; i2 < 4; ++i2) {
        const int r = rg2 * 4 + i2;
        float4 p4 = *(const float4*)&R1[r * 128 + ((mq ^ (r & 15)) << 2)];
        pq[i2][0] = p4.x; pq[i2][1] = p4.y; pq[i2][2] = p4.z; pq[i2][3] = p4.w;
      }
#pragma unroll
      for (int u = 0; u < 4; ++u) {
        const int m = half * 128 + mq * 4 + u;
        const float4 v4 = *(const float4*)(vb + m * 64 + cg2 * 4);
        const float vj[4] = {v4.x, v4.y, v4.z, v4.w};
#pragma unroll
        for (int i2 = 0; i2 < 4; ++i2)
#pragma unroll
          for (int jj = 0; jj < 4; ++jj)
            oa[i2][jj] = fmaf(pq[i2][u], vj[jj], oa[i2][jj]);
      }
    }
    __syncthreads();
  }

  // write O swizzled -> R1
#pragma unroll
  for (int i2 = 0; i2 < 4; ++i2) {
    const int r = rg2 * 4 + i2;
    *(float4*)&R1[r * 64 + ((cg2 ^ (r & 15)) << 2)] =
        make_float4(oa[i2][0], oa[i2][1], oa[i2][2], oa[i2][3]);
  }
  __syncthreads();

  // E: out = O @ wproj^T + bproj
  float ea[4][4];
#pragma unroll
  for (int i = 0; i < 4; ++i)
#pragma unroll
    for (int jj = 0; jj < 4; ++jj) ea[i][jj] = 0.f;

  for (int d4 = 0; d4 < 16; ++d4) {
    float os[4][4];
#pragma unroll
    for (int i2 = 0; i2 < 4; ++i2) {
      const int r = rg2 * 4 + i2;
      float4 o4 = *(const float4*)&R1[r * 64 + ((d4 ^ (r & 15)) << 2)];
      os[i2][0] = o4.x; os[i2][1] = o4.y; os[i2][2] = o4.z; os[i2][3] = o4.w;
    }
#pragma unroll
    for (int u = 0; u < 4; ++u) {
      const float4 w4 = *(const float4*)(wpT + (d4 * 4 + u) * 64 + cg2 * 4);
      const float wj[4] = {w4.x, w4.y, w4.z, w4.w};
#pragma unroll
      for (int i2 = 0; i2 < 4; ++i2)
#pragma unroll
        for (int jj = 0; jj < 4; ++jj)
          ea[i2][jj] = fmaf(os[i2][u], wj[jj], ea[i2][jj]);
    }
  }

  const float4 bp = *(const float4*)(bproj + cg2 * 4);
  const float bpj[4] = {bp.x, bp.y, bp.z, bp.w};
#pragma unroll
  for (int i2 = 0; i2 < 4; ++i2) {
    const int r = rg2 * 4 + i2;
    float4 o4 = make_float4(ea[i2][0] + bpj[0], ea[i2][1] + bpj[1],
                            ea[i2][2] + bpj[2], ea[i2][3] + bpj[3]);
    *(float4*)(out + ((size_t)b * kN + n0 + r) * 64 + cg2 * 4) = o4;
  }
}

}  // namespace

extern "C" void kernel_launch(void* const* d_in, const int* in_sizes, int n_in,
                              void* d_out, int out_size, void* d_ws, size_t ws_size,
                              hipStream_t stream) {
  (void)in_sizes; (void)n_in; (void)out_size; (void)ws_size;
  const float* x     = (const float*)d_in[0];
  const float* wq    = (const float*)d_in[1];
  const float* bq    = (const float*)d_in[2];
  const float* wkv   = (const float*)d_in[3];
  const float* bkv   = (const float*)d_in[4];
  const float* wproj = (const float*)d_in[5];
  const float* bproj = (const float*)d_in[6];
  const float* wsr   = (const float*)d_in[7];
  const float* gamma = (const float*)d_in[8];
  const float* beta  = (const float*)d_in[9];
  float* out = (float*)d_out;
  float* ws  = (float*)d_ws;

  k0_reorder<<<1088, 256, 0, stream>>>(wq, wkv, wproj, wsr, ws);
  k1_conv_ln_kv<<<256, 256, 0, stream>>>(x, bkv, gamma, beta, ws);
  k2_attn<<<2048, 256, 0, stream>>>(x, bq, bproj, ws, out);
}

// Round 2
// 104.688 us; speedup vs baseline: 2.2015x; 2.2015x over previous
//
#include <hip/hip_runtime.h>
#include <hip/hip_bf16.h>

// EfficientSelfAttn (PVT spatial-reduction attention), fp32 in/out.
// B=8, N=16384, C=64, NH=1, SR=8, H=W=128 -> Nk=256.
//
// R2: k2 rebuilt on v_mfma_f32_32x32x16_bf16 with 3-product bf16 hi/lo split
// (hi*hi + hi*lo + lo*hi ~ fp32 accuracy). k0/k1 emit weights and K/V
// directly in MFMA fragment layout (hi/lo planes) in ws.

namespace {

constexpr int kN = 16384;

// ---- ws byte layout ----
constexpr size_t OFF_WSRT = 0;              // f32 [r=kh*8+kw][ic][oc] 64*64*64
constexpr size_t OFF_WKVT = 1048576;        // f32 [c][j] 64*128
constexpr size_t OFF_WQF  = 1081344;        // bf16 frag [pl2][ks4][ct2][64][8]
constexpr size_t OFF_WPF  = 1097728;        // bf16 frag [pl2][ks4][ct2][64][8]
constexpr size_t OFF_KF   = 1114112;        // bf16 frag [b][pl2][tr8][ks4][64][8]
constexpr size_t OFF_VF   = 1638400;        // bf16 frag [b][pl2][ks16][ct2][64][8]
// end = 2162688 bytes

typedef __attribute__((ext_vector_type(8))) __bf16 bhalf8;
typedef __attribute__((ext_vector_type(16))) float f32x16;

#define MFMA32(a, b, c) __builtin_amdgcn_mfma_f32_32x32x16_bf16((a), (b), (c), 0, 0, 0)

__device__ __forceinline__ void split1(float x, unsigned short& h, unsigned short& l) {
  unsigned u = __float_as_uint(x);
  h = (unsigned short)(u >> 16);
  float r = x - __uint_as_float(u & 0xFFFF0000u);
  l = (unsigned short)(__float_as_uint(r) >> 16);
}

// ---- k0: weight reorder + fragment/split generation ------------------------
__global__ __launch_bounds__(256) void k0_reorder(
    const float* __restrict__ wq, const float* __restrict__ wkv,
    const float* __restrict__ wproj, const float* __restrict__ wsr,
    char* __restrict__ wsb) {
  int e = blockIdx.x * 256 + threadIdx.x;
  if (e < 262144) {
    int oc = e & 63, ic = (e >> 6) & 63, r = e >> 12;
    ((float*)(wsb + OFF_WSRT))[e] = wsr[oc * 4096 + ic * 64 + r];
  } else if (e < 270336) {
    int i = e - 262144;
    int j = i & 127, c = i >> 7;
    ((float*)(wsb + OFF_WKVT))[i] = wkv[j * 64 + c];
  } else if (e < 278528) {
    int i = e - 270336;
    bool iswp = i >= 4096;
    int ii = i & 4095;
    // ii = ((ks*2+ct)*64 + ln)*8 + e8
    int e8 = ii & 7, ln = (ii >> 3) & 63, ct = (ii >> 9) & 1, ks = ii >> 10;
    int cc = ct * 32 + (ln & 31);
    int kk = ks * 16 + (ln >> 5) * 8 + e8;
    const float* src = iswp ? wproj : wq;
    float v = src[cc * 64 + kk];  // B = W^T : element (k=kk, col=cc)
    unsigned short h, l;
    split1(v, h, l);
    size_t base = (iswp ? OFF_WPF : OFF_WQF) + (size_t)ii * 2;
    *(unsigned short*)(wsb + base) = h;
    *(unsigned short*)(wsb + base + 8192) = l;
  }
}

// ---- k1: conv + LN + KV, emits K/V hi+lo fragments -------------------------
// grid: 256 = 8 batches * 32 patch-groups (8 patches each). 256 threads.
__global__ __launch_bounds__(256) void k1_conv_ln_kv(
    const float* __restrict__ x, const float* __restrict__ bkv,
    const float* __restrict__ gamma, const float* __restrict__ beta,
    char* __restrict__ wsb) {
  const float* __restrict__ wsrT = (const float*)(wsb + OFF_WSRT);
  const float* __restrict__ wkvT = (const float*)(wsb + OFF_WKVT);

  const int b  = blockIdx.x >> 5;
  const int pg = blockIdx.x & 31;
  const int t  = threadIdx.x;
  const int ocp = t & 31;
  const int icg = t >> 5;

  __shared__ float chunk[4096];  // [p][kw][ic] for one kh slab
  __shared__ float red[4096];    // [icg][oc*8+p]
  __shared__ float cvout[512];   // [p][oc]
  __shared__ float xnl[512];     // [p][oc]

  const float* __restrict__ xb = x + (size_t)b * (kN * 64);

  float acc0[8], acc1[8];
#pragma unroll
  for (int p = 0; p < 8; ++p) { acc0[p] = 0.f; acc1[p] = 0.f; }

  for (int kh = 0; kh < 8; ++kh) {
    __syncthreads();
#pragma unroll
    for (int it = 0; it < 4; ++it) {
      int f = it * 1024 + t * 4;
      int p = f >> 9;
      int w512 = f & 511;
      int pid = pg * 8 + p;
      int oh = pid >> 4, ow = pid & 15;
      const float* src = xb + oh * 65536 + ow * 512 + kh * 8192 + w512;
      *(float4*)&chunk[f] = *(const float4*)src;
    }
    __syncthreads();
    for (int kw = 0; kw < 8; ++kw) {
      const int rbase = ((kh * 8 + kw) * 64 + icg * 8) * 64;
      float w0[8], w1[8];
#pragma unroll
      for (int ii = 0; ii < 8; ++ii) {
        w0[ii] = wsrT[rbase + ii * 64 + ocp];
        w1[ii] = wsrT[rbase + ii * 64 + ocp + 32];
      }
#pragma unroll
      for (int p = 0; p < 8; ++p) {
        const float* cp = &chunk[p * 512 + kw * 64 + icg * 8];
        float4 a = *(const float4*)cp;
        float4 bb = *(const float4*)(cp + 4);
        float xs[8] = {a.x, a.y, a.z, a.w, bb.x, bb.y, bb.z, bb.w};
#pragma unroll
        for (int ii = 0; ii < 8; ++ii) {
          acc0[p] = fmaf(w0[ii], xs[ii], acc0[p]);
          acc1[p] = fmaf(w1[ii], xs[ii], acc1[p]);
        }
      }
    }
  }

#pragma unroll
  for (int p = 0; p < 8; ++p) {
    red[icg * 512 + ocp * 8 + p] = acc0[p];
    red[icg * 512 + (ocp + 32) * 8 + p] = acc1[p];
  }
  __syncthreads();
#pragma unroll
  for (int u = 0; u < 2; ++u) {
    int e = t * 2 + u;  // e = oc*8 + p
    float s = 0.f;
#pragma unroll
    for (int g = 0; g < 8; ++g) s += red[g * 512 + e];
    cvout[(e & 7) * 64 + (e >> 3)] = s;
  }
  __syncthreads();

  const int lane = t & 63;
  const int wid = t >> 6;
#pragma unroll
  for (int pp = 0; pp < 2; ++pp) {
    int p = wid * 2 + pp;
    float val = cvout[p * 64 + lane];
    float ssum = val;
#pragma unroll
    for (int off = 1; off < 64; off <<= 1) ssum += __shfl_xor(ssum, off);
    float mean = ssum * (1.f / 64.f);
    float dv = val - mean;
    float sq = dv * dv;
#pragma unroll
    for (int off = 1; off < 64; off <<= 1) sq += __shfl_xor(sq, off);
    float rs = 1.0f / sqrtf(sq * (1.f / 64.f) + 1e-5f);
    xnl[p * 64 + lane] = dv * rs * gamma[lane] + beta[lane];
  }
  __syncthreads();

  // KV projection: pgk = t>>7 (4 patches), j = t&127
  const int pgk = t >> 7;
  const int j = t & 127;
  float a4[4] = {0.f, 0.f, 0.f, 0.f};
  for (int c = 0; c < 64; ++c) {
    float w = wkvT[c * 128 + j];
#pragma unroll
    for (int q = 0; q < 4; ++q)
      a4[q] = fmaf(xnl[(pgk * 4 + q) * 64 + c], w, a4[q]);
  }
  float bj = bkv[j];
#pragma unroll
  for (int q = 0; q < 4; ++q) {
    int p = pgk * 4 + q;
    int pid = pg * 8 + p;  // key index
    float val = a4[q] + bj;
    unsigned short h, l;
    split1(val, h, l);
    if (j < 64) {
      // K A-frag: row(key)=tr*32+(l&31), k(ic)=ks*16+(l>>5)*8+e
      int tr = pid >> 5, ks = j >> 4, e8 = j & 7;
      int ln = (pid & 31) | (((j >> 3) & 1) << 5);
      size_t base = OFF_KF + (size_t)(b * 2) * 32768 +
                    (size_t)((tr * 4 + ks) * 64 + ln) * 16 + e8 * 2;
      *(unsigned short*)(wsb + base) = h;
      *(unsigned short*)(wsb + base + 32768) = l;
    } else {
      // V B-frag: col(d)=ct*32+(l&31), k(key)=ks*16+(l>>5)*8+e
      int d = j - 64;
      int ct = d >> 5, ks = pid >> 4, e8 = pid & 7;
      int ln = (d & 31) | (((pid >> 3) & 1) << 5);
      size_t base = OFF_VF + (size_t)(b * 2) * 32768 +
                    (size_t)((ks * 2 + ct) * 64 + ln) * 16 + e8 * 2;
      *(unsigned short*)(wsb + base) = h;
      *(unsigned short*)(wsb + base + 32768) = l;
    }
  }
}

// ---- k2: MFMA attention ----------------------------------------------------
// grid: 2048 = 8 batches * 256 row-blocks (64 queries each). 4 waves.
// Wave w owns: Q/O tile (qt=w>>1, ct=w&1); S^T keys 64w..64w+63.
__global__ __launch_bounds__(256) void k2_attn(
    const float* __restrict__ x, const float* __restrict__ bq,
    const float* __restrict__ bproj, const char* __restrict__ wsb,
    float* __restrict__ out) {
  const int b  = blockIdx.x >> 8;
  const int rb = blockIdx.x & 255;
  const int n0 = rb * 64;
  const int t = threadIdx.x;
  const int w = t >> 6;
  const int lane = t & 63;
  const int l31 = lane & 31;
  const int lh = lane >> 5;
  const int qt = w >> 1, ct = w & 1;

  __shared__ __align__(16) char sm[34816];
  char* XH = sm;                         // [64 q][64 ic] bf16, swz(q&7)
  char* XL = sm + 8192;
  char* QH = sm + 16384;                 // [64 q][64 c] bf16, swz(q&7)
  char* QL = sm + 24576;
  float2* SMP = (float2*)(sm + 32768);   // [w][64 q] (m, s)
  char* PH = sm;                         // [64 q][128 key] bf16, swz(q&15)
  char* PL = sm + 16384;
  char* OH = sm;                         // [64 q][64 d] bf16, swz(q&7)
  char* OL = sm + 8192;

  const float* __restrict__ xb = x + ((size_t)b * kN + n0) * 64;

  // ---- stage X as bf16 hi/lo, swizzled ----
#pragma unroll
  for (int it = 0; it < 4; ++it) {
    int f = it * 1024 + t * 4;
    int q = f >> 6, c = f & 63;
    float4 xv = *(const float4*)(xb + f);
    unsigned short h0, l0, h1, l1, h2, l2, h3, l3;
    split1(xv.x, h0, l0); split1(xv.y, h1, l1);
    split1(xv.z, h2, l2); split1(xv.w, h3, l3);
    int off = q * 128 + ((c * 2) ^ ((q & 7) << 4));
    *(uint2*)(XH + off) = make_uint2(h0 | ((unsigned)h1 << 16), h2 | ((unsigned)h3 << 16));
    *(uint2*)(XL + off) = make_uint2(l0 | ((unsigned)l1 << 16), l2 | ((unsigned)l3 << 16));
  }
  __syncthreads();

  // ---- q-proj: Q = X @ Wq^T (+bq) * 0.125 ; write Q [q][c] hi/lo ----
  {
    f32x16 acc;
#pragma unroll
    for (int i = 0; i < 16; ++i) acc[i] = 0.f;
    const int qrow = qt * 32 + l31;
    const int rsw = (qrow & 7) << 4;
#pragma unroll
    for (int ks = 0; ks < 4; ++ks) {
      int ra = qrow * 128 + (((ks * 16 + lh * 8) * 2) ^ rsw);
      bhalf8 ah = *(const bhalf8*)(XH + ra);
      bhalf8 al = *(const bhalf8*)(XL + ra);
      const char* p = wsb + OFF_WQF + (size_t)((ks * 2 + ct) * 64 + lane) * 16;
      bhalf8 bh = *(const bhalf8*)p;
      bhalf8 bl = *(const bhalf8*)(p + 8192);
      acc = MFMA32(ah, bh, acc);
      acc = MFMA32(ah, bl, acc);
      acc = MFMA32(al, bh, acc);
    }
    int c = ct * 32 + l31;
    float bias = bq[c];
#pragma unroll
    for (int r = 0; r < 16; ++r) {
      int q = qt * 32 + (r & 3) + 8 * (r >> 2) + 4 * lh;
      float v = (acc[r] + bias) * 0.125f;
      unsigned short h, l;
      split1(v, h, l);
      int off = q * 128 + ((c * 2) ^ ((q & 7) << 4));
      *(unsigned short*)(QH + off) = h;
      *(unsigned short*)(QL + off) = l;
    }
  }
  __syncthreads();

  // ---- S^T = K @ Q^T : wave w -> keys 64w..64w+63 (tiles tr=2w,2w+1) ----
  f32x16 accS[2][2];
#pragma unroll
  for (int i = 0; i < 2; ++i)
#pragma unroll
    for (int j = 0; j < 2; ++j)
#pragma unroll
      for (int r = 0; r < 16; ++r) accS[i][j][r] = 0.f;

  const char* kf_b = wsb + OFF_KF + (size_t)(b * 2) * 32768;
#pragma unroll
  for (int i = 0; i < 2; ++i) {
    const int tr = w * 2 + i;
    bhalf8 Ah[4], Al[4];
#pragma unroll
    for (int ks = 0; ks < 4; ++ks) {
      const char* p = kf_b + (size_t)((tr * 4 + ks) * 64 + lane) * 16;
      Ah[ks] = *(const bhalf8*)p;
      Al[ks] = *(const bhalf8*)(p + 32768);
    }
#pragma unroll
    for (int j = 0; j < 2; ++j) {
      const int qq = j * 32 + l31;
      const int qsw = (qq & 7) << 4;
#pragma unroll
      for (int ks = 0; ks < 4; ++ks) {
        int off = qq * 128 + (((ks * 16 + lh * 8) * 2) ^ qsw);
        bhalf8 bh = *(const bhalf8*)(QH + off);
        bhalf8 bl = *(const bhalf8*)(QL + off);
        accS[i][j] = MFMA32(Ah[ks], bh, accS[i][j]);
        accS[i][j] = MFMA32(Ah[ks], bl, accS[i][j]);
        accS[i][j] = MFMA32(Al[ks], bh, accS[i][j]);
      }
    }
  }

  // ---- softmax over 256 keys: wave-local partials + cross-wave via LDS ----
  float mloc[2];
#pragma unroll
  for (int j = 0; j < 2; ++j) {
    float m = -1e30f;
#pragma unroll
    for (int i = 0; i < 2; ++i)
#pragma unroll
      for (int r = 0; r < 16; ++r) m = fmaxf(m, accS[i][j][r]);
    m = fmaxf(m, __shfl_xor(m, 32));
    float s = 0.f;
#pragma unroll
    for (int i = 0; i < 2; ++i)
#pragma unroll
      for (int r = 0; r < 16; ++r) {
        float e = __expf(accS[i][j][r] - m);
        accS[i][j][r] = e;
        s += e;
      }
    s += __shfl_xor(s, 32);
    mloc[j] = m;
    if (lh == 0) SMP[w * 64 + j * 32 + l31] = make_float2(m, s);
  }
  __syncthreads();
#pragma unroll
  for (int j = 0; j < 2; ++j) {
    float2 p0 = SMP[0 * 64 + j * 32 + l31];
    float2 p1 = SMP[1 * 64 + j * 32 + l31];
    float2 p2 = SMP[2 * 64 + j * 32 + l31];
    float2 p3 = SMP[3 * 64 + j * 32 + l31];
    float M = fmaxf(fmaxf(p0.x, p1.x), fmaxf(p2.x, p3.x));
    float T = p0.y * __expf(p0.x - M) + p1.y * __expf(p1.x - M) +
              p2.y * __expf(p2.x - M) + p3.y * __expf(p3.x - M);
    float f = __expf(mloc[j] - M) / T;
#pragma unroll
    for (int i = 0; i < 2; ++i)
#pragma unroll
      for (int r = 0; r < 16; ++r) accS[i][j][r] *= f;
  }

  // ---- PV in two key-halves through LDS ----
  f32x16 accO;
#pragma unroll
  for (int r = 0; r < 16; ++r) accO[r] = 0.f;

  const char* vf_b = wsb + OFF_VF + (size_t)(b * 2) * 32768;
#pragma unroll
  for (int h = 0; h < 2; ++h) {
    if ((w >> 1) == h) {
      // this wave's 64 keys belong to half h; local tile tl = 2*(w&1)+i
#pragma unroll
      for (int i = 0; i < 2; ++i) {
        const int tl = (w & 1) * 2 + i;
#pragma unroll
        for (int j = 0; j < 2; ++j) {
          const int q = j * 32 + l31;
          const int swz = (q & 15) << 4;
#pragma unroll
          for (int r = 0; r < 16; r += 2) {
            int keyloc = tl * 32 + (r & 3) + 8 * (r >> 2) + 4 * lh;
            unsigned short h0, l0, h1, l1;
            split1(accS[i][j][r], h0, l0);
            split1(accS[i][j][r + 1], h1, l1);
            int off = q * 256 + ((keyloc * 2) ^ swz);
            *(unsigned*)(PH + off) = h0 | ((unsigned)h1 << 16);
            *(unsigned*)(PL + off) = l0 | ((unsigned)l1 << 16);
          }
        }
      }
    }
    __syncthreads();
    const int qrow = qt * 32 + l31;
    const int qsw = (qrow & 15) << 4;
#pragma unroll
    for (int kg = 0; kg < 2; ++kg) {
      bhalf8 Vh[4], Vl[4];
#pragma unroll
      for (int u = 0; u < 4; ++u) {
        int ksg = h * 8 + kg * 4 + u;
        const char* p = vf_b + (size_t)((ksg * 2 + ct) * 64 + lane) * 16;
        Vh[u] = *(const bhalf8*)p;
        Vl[u] = *(const bhalf8*)(p + 32768);
      }
#pragma unroll
      for (int u = 0; u < 4; ++u) {
        int ksl = kg * 4 + u;
        int off = qrow * 256 + (((ksl * 16 + lh * 8) * 2) ^ qsw);
        bhalf8 ph = *(const bhalf8*)(PH + off);
        bhalf8 pl = *(const bhalf8*)(PL + off);
        accO = MFMA32(ph, Vh[u], accO);
        accO = MFMA32(ph, Vl[u], accO);
        accO = MFMA32(pl, Vh[u], accO);
      }
    }
    __syncthreads();
  }

  // ---- write O [q][d] hi/lo ----
  {
    const int d = ct * 32 + l31;
#pragma unroll
    for (int r = 0; r < 16; ++r) {
      int q = qt * 32 + (r & 3) + 8 * (r >> 2) + 4 * lh;
      unsigned short h, l;
      split1(accO[r], h, l);
      int off = q * 128 + ((d * 2) ^ ((q & 7) << 4));
      *(unsigned short*)(OH + off) = h;
      *(unsigned short*)(OL + off) = l;
    }
  }
  __syncthreads();

  // ---- out-proj: out = O @ Wp^T + bproj ----
  {
    f32x16 acc;
#pragma unroll
    for (int i = 0; i < 16; ++i) acc[i] = 0.f;
    const int qrow = qt * 32 + l31;
    const int rsw = (qrow & 7) << 4;
#pragma unroll
    for (int ks = 0; ks < 4; ++ks) {
      int off = qrow * 128 + (((ks * 16 + lh * 8) * 2) ^ rsw);
      bhalf8 ah = *(const bhalf8*)(OH + off);
      bhalf8 al = *(const bhalf8*)(OL + off);
      const char* p = wsb + OFF_WPF + (size_t)((ks * 2 + ct) * 64 + lane) * 16;
      bhalf8 bh = *(const bhalf8*)p;
      bhalf8 bl = *(const bhalf8*)(p + 8192);
      acc = MFMA32(ah, bh, acc);
      acc = MFMA32(ah, bl, acc);
      acc = MFMA32(al, bh, acc);
    }
    const int c = ct * 32 + l31;
    float bias = bproj[c];
    float* ob = out + ((size_t)b * kN + n0) * 64;
#pragma unroll
    for (int r = 0; r < 16; ++r) {
      int q = qt * 32 + (r & 3) + 8 * (r >> 2) + 4 * lh;
      ob[q * 64 + c] = acc[r] + bias;
    }
  }
}

}  // namespace

extern "C" void kernel_launch(void* const* d_in, const int* in_sizes, int n_in,
                              void* d_out, int out_size, void* d_ws, size_t ws_size,
                              hipStream_t stream) {
  (void)in_sizes; (void)n_in; (void)out_size; (void)ws_size;
  const float* x     = (const float*)d_in[0];
  const float* wq    = (const float*)d_in[1];
  const float* bq    = (const float*)d_in[2];
  const float* wkv   = (const float*)d_in[3];
  const float* bkv   = (const float*)d_in[4];
  const float* wproj = (const float*)d_in[5];
  const float* bproj = (const float*)d_in[6];
  const float* wsr   = (const float*)d_in[7];
  const float* gamma = (const float*)d_in[8];
  const float* beta  = (const float*)d_in[9];
  float* out = (float*)d_out;
  char* wsb  = (char*)d_ws;

  k0_reorder<<<1088, 256, 0, stream>>>(wq, wkv, wproj, wsr, wsb);
  k1_conv_ln_kv<<<256, 256, 0, stream>>>(x, bkv, gamma, beta, wsb);
  k2_attn<<<2048, 256, 0, stream>>>(x, bq, bproj, wsb, out);
}